// Round 2
// baseline (5064.850 us; speedup 1.0000x reference)
//
#include <hip/hip_runtime.h>
#include <hip/hip_bf16.h>

// ---------------------------------------------------------------------------
// Model: self/ally tanh-Linear encoders -> segment mean -> cat MLP ->
//        8192-step LSTM (H=20) -> policy/value heads.
//   k_bounds  : segment start offsets via binary search
//   k_segmean : 1 wave/segment, 2 rows/lane per LDS-weight read
//   k_feats   : 64-thr blocks x 128; writes xg PACKED as float4 per (t,unit):
//               xgp[t*20+k] = {i,f,g,o} pre-activations (bias included)
//   k_lstm    : single wave; lane k<20 computes ALL 4 gates of unit k
//               (no cross-lane in the chain except readlane h-broadcast)
//   k_heads   : 64-thr blocks x 128
// ---------------------------------------------------------------------------

#define T_STEPS 8192
#define TOTAL_ROWS 1048576
#define DSELF 128
#define DALLY 64
#define HS 20
#define NOUT 16

typedef float v2f __attribute__((ext_vector_type(2)));

__device__ __forceinline__ float rcp_f(float x) { return __builtin_amdgcn_rcpf(x); }
__device__ __forceinline__ float sigm_f(float x) { return rcp_f(1.0f + __expf(-x)); }
// tanh(x) = 2*sigmoid(2x) - 1 ; saturates correctly at +-inf
__device__ __forceinline__ float tanh_f(float x) { return fmaf(2.0f, sigm_f(2.0f * x), -1.0f); }

// --------------------------- K1: segment boundaries -------------------------
__global__ void k_bounds(const int* __restrict__ seg, int* __restrict__ start) {
  int s = blockIdx.x * blockDim.x + threadIdx.x;
  if (s > T_STEPS) return;
  if (s == T_STEPS) { start[s] = TOTAL_ROWS; return; }
  int lo = 0, hi = TOTAL_ROWS;
  while (lo < hi) {
    int mid = (lo + hi) >> 1;
    if (seg[mid] < s) lo = mid + 1; else hi = mid;
  }
  start[s] = lo;
}

// ------------------- K2: fused ally tanh-linear + segment mean --------------
// one wave per segment; each lane owns rows r and r+64 per iteration so each
// broadcast LDS weight read is amortized over 2 rows.
__global__ __launch_bounds__(64) void k_segmean(
    const float* __restrict__ ally, const int* __restrict__ start,
    const float* __restrict__ W_ally, const float* __restrict__ b_ally,
    float* __restrict__ avg) {
  __shared__ float wl[HS * DALLY];
  __shared__ float bl[HS];
  __shared__ float red[64][HS + 1];  // +1 pad: stride 21 kills bank conflicts
  const int lane = threadIdx.x;
  const int s = blockIdx.x;
  for (int i = lane; i < HS * DALLY; i += 64) wl[i] = W_ally[i];
  if (lane < HS) bl[lane] = b_ally[lane];
  __syncthreads();
  const int r0 = start[s], r1 = start[s + 1];
  float acc[HS];
#pragma unroll
  for (int h = 0; h < HS; ++h) acc[h] = 0.0f;
  for (int r = r0 + lane; r < r1; r += 128) {
    const int rb = r + 64;
    const bool has2 = rb < r1;
    const float* rowA = ally + (size_t)r * DALLY;
    const float* rowB = ally + (size_t)(has2 ? rb : r) * DALLY;
    float dA[HS], dB[HS];
#pragma unroll
    for (int h = 0; h < HS; ++h) { dA[h] = bl[h]; dB[h] = bl[h]; }
#pragma unroll
    for (int j = 0; j < DALLY / 4; ++j) {
      const float4 xa = *reinterpret_cast<const float4*>(rowA + j * 4);
      const float4 xb = *reinterpret_cast<const float4*>(rowB + j * 4);
#pragma unroll
      for (int h = 0; h < HS; ++h) {
        const float4 w = *reinterpret_cast<const float4*>(&wl[h * DALLY + j * 4]);
        dA[h] = fmaf(xa.x, w.x, dA[h]); dB[h] = fmaf(xb.x, w.x, dB[h]);
        dA[h] = fmaf(xa.y, w.y, dA[h]); dB[h] = fmaf(xb.y, w.y, dB[h]);
        dA[h] = fmaf(xa.z, w.z, dA[h]); dB[h] = fmaf(xb.z, w.z, dB[h]);
        dA[h] = fmaf(xa.w, w.w, dA[h]); dB[h] = fmaf(xb.w, w.w, dB[h]);
      }
    }
#pragma unroll
    for (int h = 0; h < HS; ++h) acc[h] += tanh_f(dA[h]);
    if (has2) {
#pragma unroll
      for (int h = 0; h < HS; ++h) acc[h] += tanh_f(dB[h]);
    }
  }
#pragma unroll
  for (int h = 0; h < HS; ++h) red[lane][h] = acc[h];
  __syncthreads();
  if (lane < HS) {
    float t = 0.0f;
    for (int l = 0; l < 64; ++l) t += red[l][lane];
    avg[(size_t)s * HS + lane] = t / (float)(r1 - r0);
  }
}

// ------------- K3: per-timestep features: s, cat, xg(packed), value ---------
__global__ __launch_bounds__(64) void k_feats(
    const float* __restrict__ self_in, const float* __restrict__ avg,
    const float* __restrict__ W_self, const float* __restrict__ b_self,
    const float* __restrict__ W_cat, const float* __restrict__ b_cat,
    const float* __restrict__ W_ih, const float* __restrict__ b_ih,
    const float* __restrict__ b_hh,
    const float* __restrict__ W_vfc, const float* __restrict__ b_vfc,
    const float* __restrict__ W_v, const float* __restrict__ b_v,
    float4* __restrict__ xgp, float* __restrict__ v_out) {
  __shared__ float s_ws[HS * DSELF];
  __shared__ float s_bs[HS];
  __shared__ float s_wc[HS * 2 * HS];
  __shared__ float s_bc[HS];
  __shared__ float s_wih[4 * HS * HS];
  __shared__ float s_bih[4 * HS];
  __shared__ float s_wv[HS * HS];
  __shared__ float s_bv[HS];
  __shared__ float s_wvv[HS];
  __shared__ float s_bvs;
  const int tid = threadIdx.x;
  for (int i = tid; i < HS * DSELF; i += 64) s_ws[i] = W_self[i];
  for (int i = tid; i < HS * 2 * HS; i += 64) s_wc[i] = W_cat[i];
  for (int i = tid; i < 4 * HS * HS; i += 64) s_wih[i] = W_ih[i];
  for (int i = tid; i < HS * HS; i += 64) s_wv[i] = W_vfc[i];
  for (int i = tid; i < 4 * HS; i += 64) s_bih[i] = b_ih[i] + b_hh[i];
  if (tid < HS) {
    s_bs[tid] = b_self[tid]; s_bc[tid] = b_cat[tid];
    s_bv[tid] = b_vfc[tid];  s_wvv[tid] = W_v[tid];
  }
  if (tid == 0) s_bvs = b_v[0];
  __syncthreads();

  const int t = blockIdx.x * 64 + tid;
  const float* srow = self_in + (size_t)t * DSELF;
  float acc[HS];
#pragma unroll
  for (int h = 0; h < HS; ++h) acc[h] = s_bs[h];
  for (int j = 0; j < DSELF / 4; ++j) {
    const float4 x = *reinterpret_cast<const float4*>(srow + j * 4);
#pragma unroll
    for (int h = 0; h < HS; ++h) {
      const float4 w = *reinterpret_cast<const float4*>(&s_ws[h * DSELF + j * 4]);
      acc[h] = fmaf(x.x, w.x, acc[h]);
      acc[h] = fmaf(x.y, w.y, acc[h]);
      acc[h] = fmaf(x.z, w.z, acc[h]);
      acc[h] = fmaf(x.w, w.w, acc[h]);
    }
  }
  float sv[HS], av[HS];
#pragma unroll
  for (int h = 0; h < HS; ++h) sv[h] = tanh_f(acc[h]);
#pragma unroll
  for (int h = 0; h < HS; ++h) av[h] = avg[(size_t)t * HS + h];
  float cat[HS];
#pragma unroll
  for (int h = 0; h < HS; ++h) {
    float a = s_bc[h];
#pragma unroll
    for (int j = 0; j < HS; ++j) a = fmaf(sv[j], s_wc[h * 2 * HS + j], a);
#pragma unroll
    for (int j = 0; j < HS; ++j) a = fmaf(av[j], s_wc[h * 2 * HS + HS + j], a);
    cat[h] = tanh_f(a);
  }
  // packed xg: xgp[t*20+k] = {pre_i, pre_f, pre_g, pre_o} for unit k
#pragma unroll 2
  for (int k = 0; k < HS; ++k) {
    float4 r;
    float a0 = s_bih[0 * HS + k], a1 = s_bih[1 * HS + k];
    float a2 = s_bih[2 * HS + k], a3 = s_bih[3 * HS + k];
#pragma unroll
    for (int j = 0; j < HS; ++j) {
      a0 = fmaf(cat[j], s_wih[(0 * HS + k) * HS + j], a0);
      a1 = fmaf(cat[j], s_wih[(1 * HS + k) * HS + j], a1);
      a2 = fmaf(cat[j], s_wih[(2 * HS + k) * HS + j], a2);
      a3 = fmaf(cat[j], s_wih[(3 * HS + k) * HS + j], a3);
    }
    r.x = a0; r.y = a1; r.z = a2; r.w = a3;
    xgp[(size_t)t * HS + k] = r;
  }
  float vacc = s_bvs;
#pragma unroll
  for (int h = 0; h < HS; ++h) {
    float a = s_bv[h];
#pragma unroll
    for (int j = 0; j < HS; ++j) a = fmaf(cat[j], s_wv[h * HS + j], a);
    vacc = fmaf(tanh_f(a), s_wvv[h], vacc);
  }
  v_out[t] = vacc;
}

// ----------------------------- K4: LSTM scan --------------------------------
// Single wave. Lane k<20 owns hidden unit k: holds W_hh rows {k,20+k,40+k,60+k}
// as float2 pairs and computes all four gate dots itself (no shfl in chain).
// h broadcast via 20x readlane. xg arrives packed: one dwordx4 per lane/step.
__global__ __launch_bounds__(64) void k_lstm(
    const float* __restrict__ xgp, const float* __restrict__ Whh,
    const float* __restrict__ h0, const float* __restrict__ c0,
    float* __restrict__ hout) {
  const int lane = threadIdx.x;
  const int k = lane < HS ? lane : HS - 1;  // clamp; lanes>=20 compute garbage
  v2f wi[10], wf[10], wg[10], wo[10];
  const v2f* ri = reinterpret_cast<const v2f*>(Whh + (size_t)(0 * HS + k) * HS);
  const v2f* rf = reinterpret_cast<const v2f*>(Whh + (size_t)(1 * HS + k) * HS);
  const v2f* rg = reinterpret_cast<const v2f*>(Whh + (size_t)(2 * HS + k) * HS);
  const v2f* ro = reinterpret_cast<const v2f*>(Whh + (size_t)(3 * HS + k) * HS);
#pragma unroll
  for (int j = 0; j < 10; ++j) { wi[j] = ri[j]; wf[j] = rf[j]; wg[j] = rg[j]; wo[j] = ro[j]; }
  v2f h2[10];
#pragma unroll
  for (int j = 0; j < 10; ++j) { h2[j].x = h0[2 * j]; h2[j].y = h0[2 * j + 1]; }
  float c = c0[k];

  const float4* xp = reinterpret_cast<const float4*>(xgp) + k;
  float4 ga = xp[0];
  float4 gb = xp[HS];

  for (int t = 0; t < T_STEPS; ++t) {
    const float4 gc = ga;
    ga = gb;
    int tp = t + 2; if (tp >= T_STEPS) tp = T_STEPS - 1;
    gb = xp[(size_t)tp * HS];

    v2f pi = {0.f, 0.f}, pf = {0.f, 0.f}, pg = {0.f, 0.f}, po = {0.f, 0.f};
#pragma unroll
    for (int j = 0; j < 10; ++j) {
      pi = __builtin_elementwise_fma(wi[j], h2[j], pi);
      pf = __builtin_elementwise_fma(wf[j], h2[j], pf);
      pg = __builtin_elementwise_fma(wg[j], h2[j], pg);
      po = __builtin_elementwise_fma(wo[j], h2[j], po);
    }
    const float aI = gc.x + (pi.x + pi.y);
    const float aF = gc.y + (pf.x + pf.y);
    const float aG = gc.z + (pg.x + pg.y);
    const float aO = gc.w + (po.x + po.y);
    const float iv = sigm_f(aI);
    const float fv = sigm_f(aF);
    const float gv = tanh_f(aG);
    const float ov = sigm_f(aO);
    c = fmaf(fv, c, iv * gv);
    const float hn = ov * tanh_f(c);
    if (lane < HS) hout[(size_t)t * HS + lane] = hn;
    const unsigned hu = __float_as_uint(hn);
#pragma unroll
    for (int j = 0; j < 10; ++j) {
      h2[j].x = __uint_as_float(__builtin_amdgcn_readlane(hu, 2 * j));
      h2[j].y = __uint_as_float(__builtin_amdgcn_readlane(hu, 2 * j + 1));
    }
  }
}

// ----------------------------- K5: output heads ------------------------------
__global__ __launch_bounds__(64) void k_heads(
    const float* __restrict__ hbuf,
    const float* __restrict__ W_pfc, const float* __restrict__ b_pfc,
    const float* __restrict__ W_mu, const float* __restrict__ b_mu,
    const float* __restrict__ W_ls, const float* __restrict__ b_ls,
    float* __restrict__ mu_out, float* __restrict__ lso_out,
    float* __restrict__ ls_out) {
  __shared__ float wp[HS * HS], bp[HS], wm[NOUT * HS], bm[NOUT], wl[NOUT * HS], bl[NOUT];
  const int tid = threadIdx.x;
  for (int i = tid; i < HS * HS; i += 64) wp[i] = W_pfc[i];
  for (int i = tid; i < NOUT * HS; i += 64) { wm[i] = W_mu[i]; wl[i] = W_ls[i]; }
  if (tid < HS) bp[tid] = b_pfc[tid];
  if (tid < NOUT) { bm[tid] = b_mu[tid]; bl[tid] = b_ls[tid]; }
  __syncthreads();
  const int t = blockIdx.x * 64 + tid;
  float hr[HS];
#pragma unroll
  for (int j = 0; j < HS; ++j) hr[j] = hbuf[(size_t)t * HS + j];
  float x[HS];
#pragma unroll
  for (int h = 0; h < HS; ++h) {
    float a = bp[h];
#pragma unroll
    for (int j = 0; j < HS; ++j) a = fmaf(hr[j], wp[h * HS + j], a);
    x[h] = tanh_f(a);
  }
#pragma unroll
  for (int m = 0; m < NOUT; ++m) {
    float a = bm[m], b = bl[m];
#pragma unroll
    for (int j = 0; j < HS; ++j) {
      a = fmaf(x[j], wm[m * HS + j], a);
      b = fmaf(x[j], wl[m * HS + j], b);
    }
    mu_out[(size_t)t * NOUT + m]  = tanh_f(a);
    ls_out[(size_t)t * NOUT + m]  = b;
    lso_out[(size_t)t * NOUT + m] = __expf(fmaxf(b, 0.0f) - 2.0f);
  }
}

// ---------------------------------------------------------------------------
extern "C" void kernel_launch(void* const* d_in, const int* in_sizes, int n_in,
                              void* d_out, int out_size, void* d_ws, size_t ws_size,
                              hipStream_t stream) {
  const float* self_in = (const float*)d_in[0];
  const float* ally_in = (const float*)d_in[1];
  const int*   seg     = (const int*)d_in[2];
  const float* W_self  = (const float*)d_in[3];
  const float* b_self  = (const float*)d_in[4];
  const float* W_ally  = (const float*)d_in[5];
  const float* b_ally  = (const float*)d_in[6];
  const float* W_cat   = (const float*)d_in[7];
  const float* b_cat   = (const float*)d_in[8];
  const float* W_ih    = (const float*)d_in[9];
  const float* W_hh    = (const float*)d_in[10];
  const float* b_ih    = (const float*)d_in[11];
  const float* b_hh    = (const float*)d_in[12];
  const float* W_pfc   = (const float*)d_in[13];
  const float* b_pfc   = (const float*)d_in[14];
  const float* W_vfc   = (const float*)d_in[15];
  const float* b_vfc   = (const float*)d_in[16];
  const float* W_mu    = (const float*)d_in[17];
  const float* b_mu    = (const float*)d_in[18];
  const float* W_ls    = (const float*)d_in[19];
  const float* b_ls    = (const float*)d_in[20];
  const float* W_v     = (const float*)d_in[21];
  const float* b_v     = (const float*)d_in[22];
  const float* h0      = (const float*)d_in[23];
  const float* c0      = (const float*)d_in[24];
  float* out = (float*)d_out;

  // workspace layout (bytes): start[8193] | avg[T*20] | xgp[T*20 float4] | hbuf[T*20]
  char* ws = (char*)d_ws;
  int*    start = (int*)(ws);
  float*  avg   = (float*)(ws + 36864);
  float4* xgp   = (float4*)(ws + 692224);
  float*  xgpf  = (float*)(ws + 692224);
  float*  hbuf  = (float*)(ws + 3313664);   // total ~3.79 MB

  // output layout: mu[T*16] | log_std_out[T*16] | v[T] | log_std[T*16]
  float* mu_out  = out;
  float* lso_out = out + 131072;
  float* v_out   = out + 262144;
  float* ls_out  = out + 270336;

  k_bounds<<<(T_STEPS + 256) / 256, 256, 0, stream>>>(seg, start);
  k_segmean<<<T_STEPS, 64, 0, stream>>>(ally_in, start, W_ally, b_ally, avg);
  k_feats<<<T_STEPS / 64, 64, 0, stream>>>(self_in, avg, W_self, b_self,
                                           W_cat, b_cat, W_ih, b_ih, b_hh,
                                           W_vfc, b_vfc, W_v, b_v, xgp, v_out);
  k_lstm<<<1, 64, 0, stream>>>(xgpf, W_hh, h0, c0, hbuf);
  k_heads<<<T_STEPS / 64, 64, 0, stream>>>(hbuf, W_pfc, b_pfc, W_mu, b_mu,
                                           W_ls, b_ls, mu_out, lso_out, ls_out);
}

// Round 3
// 2637.172 us; speedup vs baseline: 1.9206x; 1.9206x over previous
//
#include <hip/hip_runtime.h>
#include <hip/hip_bf16.h>

// ---------------------------------------------------------------------------
// Model: self/ally tanh-Linear encoders -> segment mean -> cat MLP ->
//        8192-step LSTM (H=20) -> policy/value heads.
//   k_bounds  : segment start offsets via binary search
//   k_segmean : 1 wave/segment; W via uniform (scalar-pipe) loads, no LDS w
//   k_feats   : 256-thr blocks; xg written as [t][80] rows (bias included)
//   k_lstm    : single wave, v1 gate layout (rows 0..59 pass1, o-gate pass2),
//               manual 4x unroll + 4-deep xg prefetch (covers ~900cyc HBM)
//   k_heads   : 256-thr blocks
// ---------------------------------------------------------------------------

#define T_STEPS 8192
#define TOTAL_ROWS 1048576
#define DSELF 128
#define DALLY 64
#define HS 20
#define NOUT 16

__device__ __forceinline__ float rcp_f(float x) { return __builtin_amdgcn_rcpf(x); }
__device__ __forceinline__ float sigm_f(float x) { return rcp_f(1.0f + __expf(-x)); }
// tanh(x) = 2*sigmoid(2x) - 1 ; saturates correctly at +-inf
__device__ __forceinline__ float tanh_f(float x) { return fmaf(2.0f, sigm_f(2.0f * x), -1.0f); }

// --------------------------- K1: segment boundaries -------------------------
__global__ void k_bounds(const int* __restrict__ seg, int* __restrict__ start) {
  int s = blockIdx.x * blockDim.x + threadIdx.x;
  if (s > T_STEPS) return;
  if (s == T_STEPS) { start[s] = TOTAL_ROWS; return; }
  int lo = 0, hi = TOTAL_ROWS;
  while (lo < hi) {
    int mid = (lo + hi) >> 1;
    if (seg[mid] < s) lo = mid + 1; else hi = mid;
  }
  start[s] = lo;
}

// ------------------- K2: fused ally tanh-linear + segment mean --------------
// one wave per segment; weights read via wave-uniform global accesses so the
// compiler issues them on the scalar pipe (s_load_dwordx4), overlapping the
// 1280 per-row FMAs. Only the cross-lane reduction uses LDS.
__global__ __launch_bounds__(64) void k_segmean(
    const float* __restrict__ ally, const int* __restrict__ start,
    const float* __restrict__ W_ally, const float* __restrict__ b_ally,
    float* __restrict__ avg) {
  __shared__ float red[64][HS + 1];  // +1 pad: stride 21 kills bank conflicts
  const int lane = threadIdx.x;
  const int s = blockIdx.x;
  const int r0 = start[s], r1 = start[s + 1];
  float acc[HS];
#pragma unroll
  for (int h = 0; h < HS; ++h) acc[h] = 0.0f;
  for (int r = r0 + lane; r < r1; r += 64) {
    const float* row = ally + (size_t)r * DALLY;
    float dot[HS];
#pragma unroll
    for (int h = 0; h < HS; ++h) dot[h] = b_ally[h];   // uniform -> SGPR
#pragma unroll
    for (int j = 0; j < DALLY / 4; ++j) {
      const float4 x = *reinterpret_cast<const float4*>(row + j * 4);
#pragma unroll
      for (int h = 0; h < HS; ++h) {
        const float4 w = *reinterpret_cast<const float4*>(&W_ally[h * DALLY + j * 4]);
        dot[h] = fmaf(x.x, w.x, dot[h]);
        dot[h] = fmaf(x.y, w.y, dot[h]);
        dot[h] = fmaf(x.z, w.z, dot[h]);
        dot[h] = fmaf(x.w, w.w, dot[h]);
      }
    }
#pragma unroll
    for (int h = 0; h < HS; ++h) acc[h] += tanh_f(dot[h]);
  }
#pragma unroll
  for (int h = 0; h < HS; ++h) red[lane][h] = acc[h];
  __syncthreads();
  if (lane < HS) {
    float t = 0.0f;
    for (int l = 0; l < 64; ++l) t += red[l][lane];
    avg[(size_t)s * HS + lane] = t / (float)(r1 - r0);
  }
}

// ------------- K3: per-timestep features: s, cat, xg, value head ------------
__global__ __launch_bounds__(256) void k_feats(
    const float* __restrict__ self_in, const float* __restrict__ avg,
    const float* __restrict__ W_self, const float* __restrict__ b_self,
    const float* __restrict__ W_cat, const float* __restrict__ b_cat,
    const float* __restrict__ W_ih, const float* __restrict__ b_ih,
    const float* __restrict__ b_hh,
    const float* __restrict__ W_vfc, const float* __restrict__ b_vfc,
    const float* __restrict__ W_v, const float* __restrict__ b_v,
    float* __restrict__ xg, float* __restrict__ v_out) {
  __shared__ float s_ws[HS * DSELF];
  __shared__ float s_bs[HS];
  __shared__ float s_wc[HS * 2 * HS];
  __shared__ float s_bc[HS];
  __shared__ float s_wih[4 * HS * HS];
  __shared__ float s_bih[4 * HS];
  __shared__ float s_wv[HS * HS];
  __shared__ float s_bv[HS];
  __shared__ float s_wvv[HS];
  __shared__ float s_bvs;
  const int tid = threadIdx.x;
  for (int i = tid; i < HS * DSELF; i += 256) s_ws[i] = W_self[i];
  for (int i = tid; i < HS * 2 * HS; i += 256) s_wc[i] = W_cat[i];
  for (int i = tid; i < 4 * HS * HS; i += 256) s_wih[i] = W_ih[i];
  for (int i = tid; i < HS * HS; i += 256) s_wv[i] = W_vfc[i];
  if (tid < HS) {
    s_bs[tid] = b_self[tid]; s_bc[tid] = b_cat[tid];
    s_bv[tid] = b_vfc[tid];  s_wvv[tid] = W_v[tid];
  }
  if (tid < 4 * HS) s_bih[tid] = b_ih[tid] + b_hh[tid];
  if (tid == 0) s_bvs = b_v[0];
  __syncthreads();

  const int t = blockIdx.x * 256 + tid;
  const float* srow = self_in + (size_t)t * DSELF;
  float acc[HS];
#pragma unroll
  for (int h = 0; h < HS; ++h) acc[h] = s_bs[h];
  for (int j = 0; j < DSELF / 4; ++j) {
    const float4 x = *reinterpret_cast<const float4*>(srow + j * 4);
#pragma unroll
    for (int h = 0; h < HS; ++h) {
      const float4 w = *reinterpret_cast<const float4*>(&s_ws[h * DSELF + j * 4]);
      acc[h] = fmaf(x.x, w.x, acc[h]);
      acc[h] = fmaf(x.y, w.y, acc[h]);
      acc[h] = fmaf(x.z, w.z, acc[h]);
      acc[h] = fmaf(x.w, w.w, acc[h]);
    }
  }
  float sv[HS], av[HS];
#pragma unroll
  for (int h = 0; h < HS; ++h) sv[h] = tanh_f(acc[h]);
#pragma unroll
  for (int h = 0; h < HS; ++h) av[h] = avg[(size_t)t * HS + h];
  float cat[HS];
#pragma unroll
  for (int h = 0; h < HS; ++h) {
    float a = s_bc[h];
#pragma unroll
    for (int j = 0; j < HS; ++j) a = fmaf(sv[j], s_wc[h * 2 * HS + j], a);
#pragma unroll
    for (int j = 0; j < HS; ++j) a = fmaf(av[j], s_wc[h * 2 * HS + HS + j], a);
    cat[h] = tanh_f(a);
  }
#pragma unroll 4
  for (int jj = 0; jj < 4 * HS; ++jj) {
    float a = s_bih[jj];
#pragma unroll
    for (int k = 0; k < HS; ++k) a = fmaf(cat[k], s_wih[jj * HS + k], a);
    xg[(size_t)t * 80 + jj] = a;
  }
  float vacc = s_bvs;
#pragma unroll
  for (int h = 0; h < HS; ++h) {
    float a = s_bv[h];
#pragma unroll
    for (int k = 0; k < HS; ++k) a = fmaf(cat[k], s_wv[h * HS + k], a);
    vacc = fmaf(tanh_f(a), s_wvv[h], vacc);
  }
  v_out[t] = vacc;
}

// ----------------------------- K4: LSTM scan --------------------------------
// Single wave. Pass1: lane j<60 -> gate row j (i:0..19 f:20..39 g:40..59),
// pass2: lanes 0..19 -> row 60+lane (o). h broadcast via readlane -> SGPR.
// Manual 4x unroll with 4-deep xg prefetch: loads for step t+4 issued inside
// step t's body using immediate offsets (<= 2240B, fits 13-bit imm); pointers
// advance once per 4 steps. Tail prefetch reads <=1280B past xg (lands in
// hbuf region of the workspace -- valid memory, values never consumed).
#define LSTM_STEP(X1, X2, K)                                                  \
  do {                                                                        \
    float pa0 = 0.f, pa1 = 0.f, qa0 = 0.f, qa1 = 0.f;                         \
    _Pragma("unroll") for (int j = 0; j < HS; j += 2) {                       \
      pa0 = fmaf(wa[j], h[j], pa0);                                           \
      pa1 = fmaf(wa[j + 1], h[j + 1], pa1);                                   \
      qa0 = fmaf(wb[j], h[j], qa0);                                           \
      qa1 = fmaf(wb[j + 1], h[j + 1], qa1);                                   \
    }                                                                         \
    const float a1 = (X1) + (pa0 + pa1);                                      \
    const float a2 = (X2) + (qa0 + qa1);                                      \
    (X1) = px1[(K + 4) * 80];                                                 \
    (X2) = px2[(K + 4) * 80];                                                 \
    const float z1 = fmaf(A, rcp_f(1.0f + __expf(-S * a1)), B);               \
    const float o = rcp_f(1.0f + __expf(-a2));                                \
    const float f = __shfl(z1, lane + 20);                                    \
    const float g = __shfl(z1, lane + 40);                                    \
    c = fmaf(f, c, z1 * g);                                                   \
    const float u = rcp_f(1.0f + __expf(-2.0f * c));                          \
    const float hn = fmaf(2.0f, u, -1.0f) * o;                                \
    if (lane < HS) hp[(K)*HS] = hn;                                           \
    const unsigned hu = __float_as_uint(hn);                                  \
    _Pragma("unroll") for (int j = 0; j < HS; ++j)                            \
        h[j] = __uint_as_float(__builtin_amdgcn_readlane(hu, j));             \
  } while (0)

__global__ __launch_bounds__(64) void k_lstm(
    const float* __restrict__ xg, const float* __restrict__ Whh,
    const float* __restrict__ h0, const float* __restrict__ c0,
    float* __restrict__ hout) {
  const int lane = threadIdx.x;
  const int r1 = lane < 60 ? lane : 59;          // pass1 gate row (60..63 dup)
  const int r2 = 60 + (lane < HS ? lane : 0);    // pass2 gate row (o)
  float wa[HS], wb[HS];
#pragma unroll
  for (int j = 0; j < HS; ++j) { wa[j] = Whh[r1 * HS + j]; wb[j] = Whh[r2 * HS + j]; }
  const bool tl = (lane >= 40 && lane < 60);     // tanh lanes (g gate)
  const float S = tl ? 2.0f : 1.0f;
  const float A = tl ? 2.0f : 1.0f;
  const float B = tl ? -1.0f : 0.0f;
  float h[HS];
#pragma unroll
  for (int j = 0; j < HS; ++j) h[j] = h0[j];     // uniform -> s_load
  float c = (lane < HS) ? c0[lane] : 0.0f;

  const float* px1 = xg + r1;
  const float* px2 = xg + r2;
  float x10 = px1[0],       x20 = px2[0];
  float x11 = px1[1 * 80],  x21 = px2[1 * 80];
  float x12 = px1[2 * 80],  x22 = px2[2 * 80];
  float x13 = px1[3 * 80],  x23 = px2[3 * 80];
  float* hp = hout + lane;

  for (int t = 0; t < T_STEPS; t += 4) {
    LSTM_STEP(x10, x20, 0);
    LSTM_STEP(x11, x21, 1);
    LSTM_STEP(x12, x22, 2);
    LSTM_STEP(x13, x23, 3);
    px1 += 4 * 80; px2 += 4 * 80; hp += 4 * HS;
  }
}

// ----------------------------- K5: output heads ------------------------------
__global__ __launch_bounds__(256) void k_heads(
    const float* __restrict__ hbuf,
    const float* __restrict__ W_pfc, const float* __restrict__ b_pfc,
    const float* __restrict__ W_mu, const float* __restrict__ b_mu,
    const float* __restrict__ W_ls, const float* __restrict__ b_ls,
    float* __restrict__ mu_out, float* __restrict__ lso_out,
    float* __restrict__ ls_out) {
  __shared__ float wp[HS * HS], bp[HS], wm[NOUT * HS], bm[NOUT], wl[NOUT * HS], bl[NOUT];
  const int tid = threadIdx.x;
  for (int i = tid; i < HS * HS; i += 256) wp[i] = W_pfc[i];
  for (int i = tid; i < NOUT * HS; i += 256) { wm[i] = W_mu[i]; wl[i] = W_ls[i]; }
  if (tid < HS) bp[tid] = b_pfc[tid];
  if (tid < NOUT) { bm[tid] = b_mu[tid]; bl[tid] = b_ls[tid]; }
  __syncthreads();
  const int t = blockIdx.x * 256 + tid;
  float hr[HS];
#pragma unroll
  for (int k = 0; k < HS; ++k) hr[k] = hbuf[(size_t)t * HS + k];
  float x[HS];
#pragma unroll
  for (int h = 0; h < HS; ++h) {
    float a = bp[h];
#pragma unroll
    for (int k = 0; k < HS; ++k) a = fmaf(hr[k], wp[h * HS + k], a);
    x[h] = tanh_f(a);
  }
#pragma unroll
  for (int m = 0; m < NOUT; ++m) {
    float a = bm[m], b = bl[m];
#pragma unroll
    for (int k = 0; k < HS; ++k) {
      a = fmaf(x[k], wm[m * HS + k], a);
      b = fmaf(x[k], wl[m * HS + k], b);
    }
    mu_out[(size_t)t * NOUT + m]  = tanh_f(a);
    ls_out[(size_t)t * NOUT + m]  = b;
    lso_out[(size_t)t * NOUT + m] = __expf(fmaxf(b, 0.0f) - 2.0f);
  }
}

// ---------------------------------------------------------------------------
extern "C" void kernel_launch(void* const* d_in, const int* in_sizes, int n_in,
                              void* d_out, int out_size, void* d_ws, size_t ws_size,
                              hipStream_t stream) {
  const float* self_in = (const float*)d_in[0];
  const float* ally_in = (const float*)d_in[1];
  const int*   seg     = (const int*)d_in[2];
  const float* W_self  = (const float*)d_in[3];
  const float* b_self  = (const float*)d_in[4];
  const float* W_ally  = (const float*)d_in[5];
  const float* b_ally  = (const float*)d_in[6];
  const float* W_cat   = (const float*)d_in[7];
  const float* b_cat   = (const float*)d_in[8];
  const float* W_ih    = (const float*)d_in[9];
  const float* W_hh    = (const float*)d_in[10];
  const float* b_ih    = (const float*)d_in[11];
  const float* b_hh    = (const float*)d_in[12];
  const float* W_pfc   = (const float*)d_in[13];
  const float* b_pfc   = (const float*)d_in[14];
  const float* W_vfc   = (const float*)d_in[15];
  const float* b_vfc   = (const float*)d_in[16];
  const float* W_mu    = (const float*)d_in[17];
  const float* b_mu    = (const float*)d_in[18];
  const float* W_ls    = (const float*)d_in[19];
  const float* b_ls    = (const float*)d_in[20];
  const float* W_v     = (const float*)d_in[21];
  const float* b_v     = (const float*)d_in[22];
  const float* h0      = (const float*)d_in[23];
  const float* c0      = (const float*)d_in[24];
  float* out = (float*)d_out;

  // workspace layout (bytes): start[8193] | avg[T*20] | xg[T*80] | hbuf[T*20]
  char* ws = (char*)d_ws;
  int*   start = (int*)(ws);
  float* avg   = (float*)(ws + 36864);
  float* xg    = (float*)(ws + 692224);
  float* hbuf  = (float*)(ws + 3313664);   // total ~3.97 MB

  // output layout: mu[T*16] | log_std_out[T*16] | v[T] | log_std[T*16]
  float* mu_out  = out;
  float* lso_out = out + 131072;
  float* v_out   = out + 262144;
  float* ls_out  = out + 270336;

  k_bounds<<<(T_STEPS + 256) / 256, 256, 0, stream>>>(seg, start);
  k_segmean<<<T_STEPS, 64, 0, stream>>>(ally_in, start, W_ally, b_ally, avg);
  k_feats<<<T_STEPS / 256, 256, 0, stream>>>(self_in, avg, W_self, b_self,
                                             W_cat, b_cat, W_ih, b_ih, b_hh,
                                             W_vfc, b_vfc, W_v, b_v, xg, v_out);
  k_lstm<<<1, 64, 0, stream>>>(xg, W_hh, h0, c0, hbuf);
  k_heads<<<T_STEPS / 256, 256, 0, stream>>>(hbuf, W_pfc, b_pfc, W_mu, b_mu,
                                             W_ls, b_ls, mu_out, lso_out, ls_out);
}

// Round 4
// 1943.614 us; speedup vs baseline: 2.6059x; 1.3568x over previous
//
#include <hip/hip_runtime.h>
#include <hip/hip_bf16.h>

// ---------------------------------------------------------------------------
// Model: self/ally tanh-Linear encoders -> segment mean -> cat MLP ->
//        8192-step LSTM (H=20) -> policy/value heads.
//   k_bounds  : segment start offsets via binary search
//   k_segmean : 1 wave/segment; coalesced 64-row LDS tiles; W via scalar loads
//   k_feats   : 256-thr blocks; xg written float4 (bias included)
//   k_lstm    : single wave; pass1 i(lanes0-19)/f(lanes32-51), pass2
//               g(lanes0-19, LOCAL)/o(lanes32-51); cross-lane f,o via
//               v_permlane32_swap (VALU) instead of ds_bpermute (LDS);
//               4x unroll + 4-deep xg prefetch
//   k_heads   : 256-thr blocks, float4 loads/stores
// ---------------------------------------------------------------------------

#define T_STEPS 8192
#define TOTAL_ROWS 1048576
#define DSELF 128
#define DALLY 64
#define HS 20
#define NOUT 16

__device__ __forceinline__ float rcp_f(float x) { return __builtin_amdgcn_rcpf(x); }
__device__ __forceinline__ float sigm_f(float x) { return rcp_f(1.0f + __expf(-x)); }
// tanh(x) = 2*sigmoid(2x) - 1 ; saturates correctly at +-inf
__device__ __forceinline__ float tanh_f(float x) { return fmaf(2.0f, sigm_f(2.0f * x), -1.0f); }

// --------------------------- K1: segment boundaries -------------------------
__global__ void k_bounds(const int* __restrict__ seg, int* __restrict__ start) {
  int s = blockIdx.x * blockDim.x + threadIdx.x;
  if (s > T_STEPS) return;
  if (s == T_STEPS) { start[s] = TOTAL_ROWS; return; }
  int lo = 0, hi = TOTAL_ROWS;
  while (lo < hi) {
    int mid = (lo + hi) >> 1;
    if (seg[mid] < s) lo = mid + 1; else hi = mid;
  }
  start[s] = lo;
}

// ------------------- K2: fused ally tanh-linear + segment mean --------------
// one wave per segment. Rows staged through LDS in 64-row tiles so global
// loads are fully coalesced (wave reads 1KB contiguous per instruction).
// Tile row stride 66 floats: 8B-aligned for float2 ds_reads, 2-way-max banks.
__global__ __launch_bounds__(64) void k_segmean(
    const float* __restrict__ ally, const int* __restrict__ start,
    const float* __restrict__ W_ally, const float* __restrict__ b_ally,
    float* __restrict__ avg) {
  __shared__ float tile[64][DALLY + 2];
  __shared__ float red[64][HS + 1];
  const int lane = threadIdx.x;
  const int s = blockIdx.x;
  const int r0 = start[s], r1 = start[s + 1];
  float acc[HS];
#pragma unroll
  for (int h = 0; h < HS; ++h) acc[h] = 0.0f;
  for (int base = r0; base < r1; base += 64) {
    const int m = min(64, r1 - base);
    __syncthreads();  // protect tile from previous iteration's readers
    for (int idx = lane; idx < m * 16; idx += 64) {
      const int rr = idx >> 4, cc = (idx & 15) << 2;
      const float4 v = *reinterpret_cast<const float4*>(
          ally + (size_t)(base + rr) * DALLY + cc);
      *reinterpret_cast<float2*>(&tile[rr][cc])     = make_float2(v.x, v.y);
      *reinterpret_cast<float2*>(&tile[rr][cc + 2]) = make_float2(v.z, v.w);
    }
    __syncthreads();
    if (lane < m) {
      float dot[HS];
#pragma unroll
      for (int h = 0; h < HS; ++h) dot[h] = b_ally[h];  // uniform -> SGPR
#pragma unroll
      for (int j = 0; j < DALLY; j += 4) {
        const float2 xa = *reinterpret_cast<const float2*>(&tile[lane][j]);
        const float2 xb = *reinterpret_cast<const float2*>(&tile[lane][j + 2]);
#pragma unroll
        for (int h = 0; h < HS; ++h) {
          const float4 w = *reinterpret_cast<const float4*>(&W_ally[h * DALLY + j]);
          dot[h] = fmaf(xa.x, w.x, dot[h]);
          dot[h] = fmaf(xa.y, w.y, dot[h]);
          dot[h] = fmaf(xb.x, w.z, dot[h]);
          dot[h] = fmaf(xb.y, w.w, dot[h]);
        }
      }
#pragma unroll
      for (int h = 0; h < HS; ++h) acc[h] += tanh_f(dot[h]);
    }
  }
#pragma unroll
  for (int h = 0; h < HS; ++h) red[lane][h] = acc[h];
  __syncthreads();
  if (lane < HS) {
    float t = 0.0f;
    for (int l = 0; l < 64; ++l) t += red[l][lane];
    avg[(size_t)s * HS + lane] = t / (float)(r1 - r0);
  }
}

// ------------- K3: per-timestep features: s, cat, xg, value head ------------
__global__ __launch_bounds__(256) void k_feats(
    const float* __restrict__ self_in, const float* __restrict__ avg,
    const float* __restrict__ W_self, const float* __restrict__ b_self,
    const float* __restrict__ W_cat, const float* __restrict__ b_cat,
    const float* __restrict__ W_ih, const float* __restrict__ b_ih,
    const float* __restrict__ b_hh,
    const float* __restrict__ W_vfc, const float* __restrict__ b_vfc,
    const float* __restrict__ W_v, const float* __restrict__ b_v,
    float* __restrict__ xg, float* __restrict__ v_out) {
  __shared__ float s_ws[HS * DSELF];
  __shared__ float s_bs[HS];
  __shared__ float s_wc[HS * 2 * HS];
  __shared__ float s_bc[HS];
  __shared__ float s_wih[4 * HS * HS];
  __shared__ float s_bih[4 * HS];
  __shared__ float s_wv[HS * HS];
  __shared__ float s_bv[HS];
  __shared__ float s_wvv[HS];
  __shared__ float s_bvs;
  const int tid = threadIdx.x;
  for (int i = tid; i < HS * DSELF; i += 256) s_ws[i] = W_self[i];
  for (int i = tid; i < HS * 2 * HS; i += 256) s_wc[i] = W_cat[i];
  for (int i = tid; i < 4 * HS * HS; i += 256) s_wih[i] = W_ih[i];
  for (int i = tid; i < HS * HS; i += 256) s_wv[i] = W_vfc[i];
  if (tid < HS) {
    s_bs[tid] = b_self[tid]; s_bc[tid] = b_cat[tid];
    s_bv[tid] = b_vfc[tid];  s_wvv[tid] = W_v[tid];
  }
  if (tid < 4 * HS) s_bih[tid] = b_ih[tid] + b_hh[tid];
  if (tid == 0) s_bvs = b_v[0];
  __syncthreads();

  const int t = blockIdx.x * 256 + tid;
  const float* srow = self_in + (size_t)t * DSELF;
  float acc[HS];
#pragma unroll
  for (int h = 0; h < HS; ++h) acc[h] = s_bs[h];
  for (int j = 0; j < DSELF / 4; ++j) {
    const float4 x = *reinterpret_cast<const float4*>(srow + j * 4);
#pragma unroll
    for (int h = 0; h < HS; ++h) {
      const float4 w = *reinterpret_cast<const float4*>(&s_ws[h * DSELF + j * 4]);
      acc[h] = fmaf(x.x, w.x, acc[h]);
      acc[h] = fmaf(x.y, w.y, acc[h]);
      acc[h] = fmaf(x.z, w.z, acc[h]);
      acc[h] = fmaf(x.w, w.w, acc[h]);
    }
  }
  float sv[HS], av[HS];
#pragma unroll
  for (int h = 0; h < HS; ++h) sv[h] = tanh_f(acc[h]);
  {
    const float4* ap = reinterpret_cast<const float4*>(avg + (size_t)t * HS);
#pragma unroll
    for (int q = 0; q < HS / 4; ++q) {
      const float4 a4 = ap[q];
      av[q * 4 + 0] = a4.x; av[q * 4 + 1] = a4.y;
      av[q * 4 + 2] = a4.z; av[q * 4 + 3] = a4.w;
    }
  }
  float cat[HS];
#pragma unroll
  for (int h = 0; h < HS; ++h) {
    float a = s_bc[h];
#pragma unroll
    for (int j = 0; j < HS; ++j) a = fmaf(sv[j], s_wc[h * 2 * HS + j], a);
#pragma unroll
    for (int j = 0; j < HS; ++j) a = fmaf(av[j], s_wc[h * 2 * HS + HS + j], a);
    cat[h] = tanh_f(a);
  }
  // xg written as float4 groups of gate rows (i,f,g,o row-major order 0..79)
#pragma unroll 2
  for (int jj = 0; jj < 4 * HS; jj += 4) {
    float a0 = s_bih[jj], a1 = s_bih[jj + 1], a2 = s_bih[jj + 2], a3 = s_bih[jj + 3];
#pragma unroll
    for (int k = 0; k < HS; ++k) {
      const float cv = cat[k];
      a0 = fmaf(cv, s_wih[(jj + 0) * HS + k], a0);
      a1 = fmaf(cv, s_wih[(jj + 1) * HS + k], a1);
      a2 = fmaf(cv, s_wih[(jj + 2) * HS + k], a2);
      a3 = fmaf(cv, s_wih[(jj + 3) * HS + k], a3);
    }
    float4 o4; o4.x = a0; o4.y = a1; o4.z = a2; o4.w = a3;
    *reinterpret_cast<float4*>(&xg[(size_t)t * 80 + jj]) = o4;
  }
  float vacc = s_bvs;
#pragma unroll
  for (int h = 0; h < HS; ++h) {
    float a = s_bv[h];
#pragma unroll
    for (int k = 0; k < HS; ++k) a = fmaf(cat[k], s_wv[h * HS + k], a);
    vacc = fmaf(tanh_f(a), s_wvv[h], vacc);
  }
  v_out[t] = vacc;
}

// ----------------------------- K4: LSTM scan --------------------------------
// Single wave. Gate->lane map:
//   pass1: lanes 0-19 -> i rows 0-19;  lanes 32-51 -> f rows 20-39
//   pass2: lanes 0-19 -> g rows 40-59; lanes 32-51 -> o rows 60-79
// Lane k<20 gets f_k and o_k from lane 32+k via v_permlane32_swap (VALU,
// replaces ds_bpermute + lgkmcnt wait). i*g is lane-local. h broadcast via
// readlane -> SGPR. 4x unroll, 4-deep xg prefetch (tail reads spill <=1280B
// into the hbuf region: valid memory, values never consumed).
#define LSTM_STEP(X1, X2, K)                                                  \
  do {                                                                        \
    float p0 = 0.f, p1 = 0.f, p2 = 0.f, p3 = 0.f;                             \
    float q0 = 0.f, q1 = 0.f, q2 = 0.f, q3 = 0.f;                             \
    _Pragma("unroll") for (int j = 0; j < HS; j += 4) {                       \
      p0 = fmaf(wa[j],     h[j],     p0); q0 = fmaf(wb[j],     h[j],     q0); \
      p1 = fmaf(wa[j + 1], h[j + 1], p1); q1 = fmaf(wb[j + 1], h[j + 1], q1); \
      p2 = fmaf(wa[j + 2], h[j + 2], p2); q2 = fmaf(wb[j + 2], h[j + 2], q2); \
      p3 = fmaf(wa[j + 3], h[j + 3], p3); q3 = fmaf(wb[j + 3], h[j + 3], q3); \
    }                                                                         \
    const float a1 = (X1) + ((p0 + p1) + (p2 + p3));                          \
    const float a2 = (X2) + ((q0 + q1) + (q2 + q3));                          \
    (X1) = px1[(K + 4) * 80];                                                 \
    (X2) = px2[(K + 4) * 80];                                                 \
    const float t1 = rcp_f(1.0f + __expf(-a1));               /* i | f */     \
    const float t2 = fmaf(A, rcp_f(1.0f + __expf(-S * a2)), B); /* g | o */   \
    auto rf = __builtin_amdgcn_permlane32_swap(                               \
        __float_as_uint(t1), __float_as_uint(t1), false, false);              \
    auto ro = __builtin_amdgcn_permlane32_swap(                               \
        __float_as_uint(t2), __float_as_uint(t2), false, false);              \
    const float fp = __uint_as_float(rf[1]);   /* lane k: t1[k+32] = f_k */   \
    const float op = __uint_as_float(ro[1]);   /* lane k: t2[k+32] = o_k */   \
    c = fmaf(fp, c, t1 * t2);                                                 \
    const float u = rcp_f(1.0f + __expf(-2.0f * c));                          \
    const float hn = fmaf(2.0f, u, -1.0f) * op;                               \
    if (lane < HS) hp[(K)*HS] = hn;                                           \
    const unsigned hu = __float_as_uint(hn);                                  \
    _Pragma("unroll") for (int j = 0; j < HS; ++j)                            \
        h[j] = __uint_as_float(__builtin_amdgcn_readlane(hu, j));             \
  } while (0)

__global__ __launch_bounds__(64) void k_lstm(
    const float* __restrict__ xg, const float* __restrict__ Whh,
    const float* __restrict__ h0, const float* __restrict__ c0,
    float* __restrict__ hout) {
  const int lane = threadIdx.x;
  const int kk = lane & 31;
  const int kc = kk < HS ? kk : HS - 1;            // clamp dup lanes
  const int r1 = kc + ((lane >= 32) ? HS : 0);     // i rows | f rows
  const int r2 = r1 + 2 * HS;                      // g rows | o rows
  float wa[HS], wb[HS];
#pragma unroll
  for (int j = 0; j < HS; ++j) { wa[j] = Whh[r1 * HS + j]; wb[j] = Whh[r2 * HS + j]; }
  // pass2 nonlinearity: tanh (g) on lanes<32, sigmoid (o) on lanes>=32
  const bool th = (lane < 32);
  const float S = th ? 2.0f : 1.0f;
  const float A = th ? 2.0f : 1.0f;
  const float B = th ? -1.0f : 0.0f;
  float h[HS];
#pragma unroll
  for (int j = 0; j < HS; ++j) h[j] = h0[j];       // uniform -> s_load
  float c = c0[kc];                                // valid where needed (k<20)

  const float* px1 = xg + r1;
  const float* px2 = xg + r2;
  float x10 = px1[0],      x20 = px2[0];
  float x11 = px1[1 * 80], x21 = px2[1 * 80];
  float x12 = px1[2 * 80], x22 = px2[2 * 80];
  float x13 = px1[3 * 80], x23 = px2[3 * 80];
  float* hp = hout + lane;

  for (int t = 0; t < T_STEPS; t += 4) {
    LSTM_STEP(x10, x20, 0);
    LSTM_STEP(x11, x21, 1);
    LSTM_STEP(x12, x22, 2);
    LSTM_STEP(x13, x23, 3);
    px1 += 4 * 80; px2 += 4 * 80; hp += 4 * HS;
  }
}

// ----------------------------- K5: output heads ------------------------------
__global__ __launch_bounds__(256) void k_heads(
    const float* __restrict__ hbuf,
    const float* __restrict__ W_pfc, const float* __restrict__ b_pfc,
    const float* __restrict__ W_mu, const float* __restrict__ b_mu,
    const float* __restrict__ W_ls, const float* __restrict__ b_ls,
    float* __restrict__ mu_out, float* __restrict__ lso_out,
    float* __restrict__ ls_out) {
  __shared__ float wp[HS * HS], bp[HS], wm[NOUT * HS], bm[NOUT], wl[NOUT * HS], bl[NOUT];
  const int tid = threadIdx.x;
  for (int i = tid; i < HS * HS; i += 256) wp[i] = W_pfc[i];
  for (int i = tid; i < NOUT * HS; i += 256) { wm[i] = W_mu[i]; wl[i] = W_ls[i]; }
  if (tid < HS) bp[tid] = b_pfc[tid];
  if (tid < NOUT) { bm[tid] = b_mu[tid]; bl[tid] = b_ls[tid]; }
  __syncthreads();
  const int t = blockIdx.x * 256 + tid;
  float hr[HS];
  {
    const float4* hp4 = reinterpret_cast<const float4*>(hbuf + (size_t)t * HS);
#pragma unroll
    for (int q = 0; q < HS / 4; ++q) {
      const float4 h4 = hp4[q];
      hr[q * 4 + 0] = h4.x; hr[q * 4 + 1] = h4.y;
      hr[q * 4 + 2] = h4.z; hr[q * 4 + 3] = h4.w;
    }
  }
  float x[HS];
#pragma unroll
  for (int h = 0; h < HS; ++h) {
    float a = bp[h];
#pragma unroll
    for (int k = 0; k < HS; ++k) a = fmaf(hr[k], wp[h * HS + k], a);
    x[h] = tanh_f(a);
  }
  float4* mo4 = reinterpret_cast<float4*>(mu_out + (size_t)t * NOUT);
  float4* lo4 = reinterpret_cast<float4*>(lso_out + (size_t)t * NOUT);
  float4* lb4 = reinterpret_cast<float4*>(ls_out + (size_t)t * NOUT);
#pragma unroll
  for (int m = 0; m < NOUT; m += 4) {
    float4 mu4, lsb4, lso4;
    float am[4], bm_[4];
#pragma unroll
    for (int q = 0; q < 4; ++q) { am[q] = bm[m + q]; bm_[q] = bl[m + q]; }
#pragma unroll
    for (int k = 0; k < HS; ++k) {
      const float xv = x[k];
#pragma unroll
      for (int q = 0; q < 4; ++q) {
        am[q]  = fmaf(xv, wm[(m + q) * HS + k], am[q]);
        bm_[q] = fmaf(xv, wl[(m + q) * HS + k], bm_[q]);
      }
    }
    mu4.x = tanh_f(am[0]); mu4.y = tanh_f(am[1]);
    mu4.z = tanh_f(am[2]); mu4.w = tanh_f(am[3]);
    lsb4.x = bm_[0]; lsb4.y = bm_[1]; lsb4.z = bm_[2]; lsb4.w = bm_[3];
    lso4.x = __expf(fmaxf(bm_[0], 0.0f) - 2.0f);
    lso4.y = __expf(fmaxf(bm_[1], 0.0f) - 2.0f);
    lso4.z = __expf(fmaxf(bm_[2], 0.0f) - 2.0f);
    lso4.w = __expf(fmaxf(bm_[3], 0.0f) - 2.0f);
    mo4[m / 4] = mu4; lb4[m / 4] = lsb4; lo4[m / 4] = lso4;
  }
}

// ---------------------------------------------------------------------------
extern "C" void kernel_launch(void* const* d_in, const int* in_sizes, int n_in,
                              void* d_out, int out_size, void* d_ws, size_t ws_size,
                              hipStream_t stream) {
  const float* self_in = (const float*)d_in[0];
  const float* ally_in = (const float*)d_in[1];
  const int*   seg     = (const int*)d_in[2];
  const float* W_self  = (const float*)d_in[3];
  const float* b_self  = (const float*)d_in[4];
  const float* W_ally  = (const float*)d_in[5];
  const float* b_ally  = (const float*)d_in[6];
  const float* W_cat   = (const float*)d_in[7];
  const float* b_cat   = (const float*)d_in[8];
  const float* W_ih    = (const float*)d_in[9];
  const float* W_hh    = (const float*)d_in[10];
  const float* b_ih    = (const float*)d_in[11];
  const float* b_hh    = (const float*)d_in[12];
  const float* W_pfc   = (const float*)d_in[13];
  const float* b_pfc   = (const float*)d_in[14];
  const float* W_vfc   = (const float*)d_in[15];
  const float* b_vfc   = (const float*)d_in[16];
  const float* W_mu    = (const float*)d_in[17];
  const float* b_mu    = (const float*)d_in[18];
  const float* W_ls    = (const float*)d_in[19];
  const float* b_ls    = (const float*)d_in[20];
  const float* W_v     = (const float*)d_in[21];
  const float* b_v     = (const float*)d_in[22];
  const float* h0      = (const float*)d_in[23];
  const float* c0      = (const float*)d_in[24];
  float* out = (float*)d_out;

  // workspace layout (bytes): start[8193] | avg[T*20] | xg[T*80] | hbuf[T*20]
  char* ws = (char*)d_ws;
  int*   start = (int*)(ws);
  float* avg   = (float*)(ws + 36864);
  float* xg    = (float*)(ws + 692224);
  float* hbuf  = (float*)(ws + 3313664);   // total ~3.97 MB

  // output layout: mu[T*16] | log_std_out[T*16] | v[T] | log_std[T*16]
  float* mu_out  = out;
  float* lso_out = out + 131072;
  float* v_out   = out + 262144;
  float* ls_out  = out + 270336;

  k_bounds<<<(T_STEPS + 256) / 256, 256, 0, stream>>>(seg, start);
  k_segmean<<<T_STEPS, 64, 0, stream>>>(ally_in, start, W_ally, b_ally, avg);
  k_feats<<<T_STEPS / 256, 256, 0, stream>>>(self_in, avg, W_self, b_self,
                                             W_cat, b_cat, W_ih, b_ih, b_hh,
                                             W_vfc, b_vfc, W_v, b_v, xg, v_out);
  k_lstm<<<1, 64, 0, stream>>>(xg, W_hh, h0, c0, hbuf);
  k_heads<<<T_STEPS / 256, 256, 0, stream>>>(hbuf, W_pfc, b_pfc, W_mu, b_mu,
                                             W_ls, b_ls, mu_out, lso_out, ls_out);
}